// Round 6
// baseline (319.556 us; speedup 1.0000x reference)
//
#include <hip/hip_runtime.h>

// DIN attention unit, MI355X — round 12: coalesced LDS-staged keys.
// R6-R11 invariant: every pass body = 63-70us regardless of NPOS, weight
// path (LDS/s_load), or occupancy -> none of those were the limiter. The
// common factor: thread-per-row key loads = 80B lane stride, so each
// float4 wave-load spans 81 cache lines (vs 16 coalesced) -> VMEM
// segment-bound + unhideable latency. Fix: stage 256-row tiles to LDS via
// async global_load_lds width=16 (contiguous global, linear LDS dest =
// wave-uniform base + lane*16), double-buffered so tile s+1 streams during
// tile s compute; rows then read from LDS via ds_read_b128.
// Cooperative path DROPPED (4 rounds, never beat split). 4 dispatches.
// launch_bounds(256,2): allocator budget model = 256/min_waves -> cap 128
// (R10's (256,4) forced 64 VGPR -> spills). LDS 41KB -> 3 blocks/CU.
// mask input UNUSED (reference uses unmasked scores — reproduced bug).

#define BB 512
#define TT 2048
#define DD 20
#define C0 32
#define C1 16

#define NTH 256              // 4 waves/block; also rows per tile
#define TILE 256             // rows per stage step (== NTH)
#define CHUNK 1024           // rows per block
#define SPB (CHUNK / TILE)   // 4 steps per block
#define NBLK (TT / CHUNK)    // 2 blocks per batch
#define GRID (BB * NBLK)     // 1024 blocks
#define NSLOT 8              // atomic slot-split

// ws float offsets
#define WS_P1 0              // 8 slots * (32 sum + 32 sq)
#define WS_P2 512            // 8 slots * (16 sum + 16 sq)
#define WS_ZERO_N 768
#define WS_BLOB 896
#define BLOB_J 24            // 20 wM + c + pad
#define BLOB_B (C0 * BLOB_J)

#define PIN(x) asm volatile("" : "+v"(x))
#define AGLOAD(p) \
    __hip_atomic_load((p), __ATOMIC_RELAXED, __HIP_MEMORY_SCOPE_AGENT)

#define GAS __attribute__((address_space(1)))
#define LAS __attribute__((address_space(3)))

__device__ __forceinline__ float fast_sigmoid(float x) {
    return __builtin_amdgcn_rcpf(1.0f + __expf(-x));
}

// Stage one 256-row tile (20480 B) to LDS, fully coalesced, async.
// Wave w covers bytes [w*5120, (w+1)*5120): 5 x global_load_lds(16B).
// LDS dest is wave-uniform base + lane*16 (linear layout requirement).
__device__ __forceinline__ void stage_tile(const float* __restrict__ gsrc,
                                           float* lbuf, int wave, int lane) {
    const float* gw = gsrc + wave * 1280 + lane * 4;  // floats
    float* lw_ = lbuf + wave * 1280;
#pragma unroll
    for (int u = 0; u < 5; ++u)
        __builtin_amdgcn_global_load_lds((const GAS void*)(gw + u * 256),
                                         (LAS void*)(lw_ + u * 256), 16, 0,
                                         0);
}

// Read my row (80 B, 16B-aligned) from LDS into registers: 5x ds_read_b128.
__device__ __forceinline__ void load_row_lds(const float* __restrict__ row,
                                             float* kk) {
    const float4* r4 = (const float4*)row;
    float4 a = r4[0], b = r4[1], c = r4[2], d = r4[3], e = r4[4];
    kk[0] = a.x; kk[1] = a.y; kk[2] = a.z; kk[3] = a.w;
    kk[4] = b.x; kk[5] = b.y; kk[6] = b.z; kk[7] = b.w;
    kk[8] = c.x; kk[9] = c.y; kk[10] = c.z; kk[11] = c.w;
    kk[12] = d.x; kk[13] = d.y; kk[14] = d.z; kk[15] = d.w;
    kk[16] = e.x; kk[17] = e.y; kk[18] = e.z; kk[19] = e.w;
}

// ---------------- prep: fold query into layer-1 weights ----------------
// Also zeroes the ws sums area and the output.
__global__ void prep_kernel(const float* __restrict__ query,
                            const float* __restrict__ W0,
                            const float* __restrict__ b0,
                            float* __restrict__ blob, float* __restrict__ ws,
                            float* __restrict__ out) {
    const int b = blockIdx.x * 2 + (threadIdx.x >> 5);
    const int j = threadIdx.x & 31;
    if (blockIdx.x == 0) {
        for (int i = threadIdx.x; i < WS_ZERO_N; i += 64) ws[i] = 0.f;
    }
    if (j < DD) out[b * DD + j] = 0.f;
    float cj = b0[j];
    float* dst = blob + (size_t)b * BLOB_B + j * BLOB_J;
#pragma unroll
    for (int d = 0; d < DD; ++d) {
        float w_q = W0[d * C0 + j];
        float w_k = W0[(DD + d) * C0 + j];
        float w_d = W0[(2 * DD + d) * C0 + j];
        float w_p = W0[(3 * DD + d) * C0 + j];
        float qd = query[b * DD + d];
        dst[d] = w_k - w_d + qd * w_p;
        cj = fmaf(qd, w_q + w_d, cj);
    }
    dst[20] = cj;
}

// ================= finalize helpers (heads of pass2/pass3) =============
__device__ __forceinline__ void finalize0(int tid, float* __restrict__ ws,
                                          float2* __restrict__ lss0) {
    if (tid < C0) {
        float sv = 0.f, qv = 0.f;
#pragma unroll
        for (int k = 0; k < NSLOT; ++k) {
            sv += AGLOAD(&ws[WS_P1 + k * (2 * C0) + tid]);
            qv += AGLOAD(&ws[WS_P1 + k * (2 * C0) + C0 + tid]);
        }
        const float invN = 1.0f / (float)(BB * TT);
        float mean = sv * invN;
        float var = qv * invN - mean * mean;
        float sc = rsqrtf(var + 1e-9f);
        lss0[tid] = make_float2(sc, -mean * sc);
    }
}

__device__ __forceinline__ void finalize1(int tid, float* __restrict__ ws,
                                          const float* __restrict__ a1,
                                          const float* __restrict__ wk,
                                          float4* __restrict__ ld1v) {
    if (tid < C1) {
        float sv = 0.f, qv = 0.f;
#pragma unroll
        for (int k = 0; k < NSLOT; ++k) {
            sv += AGLOAD(&ws[WS_P2 + k * (2 * C1) + tid]);
            qv += AGLOAD(&ws[WS_P2 + k * (2 * C1) + C1 + tid]);
        }
        const float invN = 1.0f / (float)(BB * TT);
        float mean = sv * invN;
        float var = qv * invN - mean * mean;
        float sc = rsqrtf(var + 1e-9f);
        ld1v[tid] = make_float4(sc, -mean * sc, a1[tid], wk[tid]);
    }
}

// ---------------- pass 1: layer-1 pre-activation stats ----------------
__global__ __launch_bounds__(NTH, 2) void pass1_kernel(
    const float* __restrict__ keys, const float* __restrict__ blob,
    float* __restrict__ ws) {
    const int batch = blockIdx.x >> 1, chunk = blockIdx.x & 1;
    const int slot = blockIdx.x & (NSLOT - 1);
    const int tid = threadIdx.x, wave = tid >> 6, lane = tid & 63;
    const float* bA = blob + (size_t)batch * BLOB_B;
    const float* kbase = keys + ((size_t)batch * TT + chunk * CHUNK) * DD;

    __shared__ __align__(16) float kbuf[2][TILE * DD];

    float s[C0], q[C0];
#pragma unroll
    for (int j = 0; j < C0; ++j) { s[j] = 0.f; q[j] = 0.f; }

    stage_tile(kbase, kbuf[0], wave, lane);
    __syncthreads();
#pragma unroll 1
    for (int st = 0; st < SPB; ++st) {
        const int buf = st & 1;
        if (st + 1 < SPB)
            stage_tile(kbase + (size_t)(st + 1) * TILE * DD, kbuf[buf ^ 1],
                       wave, lane);
        float kk[DD];
        load_row_lds(&kbuf[buf][tid * DD], kk);
#pragma unroll
        for (int d = 0; d < DD; ++d) PIN(kk[d]);
#pragma unroll
        for (int j = 0; j < C0; ++j) {
            const float* wr = bA + j * BLOB_J;  // uniform -> s_load
            float hh = wr[20];
#pragma unroll
            for (int d = 0; d < DD; ++d) hh = fmaf(kk[d], wr[d], hh);
            s[j] += hh;
            q[j] = fmaf(hh, hh, q[j]);
        }
        __syncthreads();
    }
    float redv = 0.f;
#pragma unroll
    for (int v = 0; v < 2 * C0; ++v) {
        float val = (v < C0) ? s[v] : q[v - C0];
#pragma unroll
        for (int o = 32; o >= 1; o >>= 1) val += __shfl_xor(val, o);
        if (lane == v) redv = val;
    }
    atomicAdd(&ws[WS_P1 + slot * (2 * C0) + lane], redv);
}

// ---------------- pass 2: layer-2 pre-activation stats ----------------
__global__ __launch_bounds__(NTH, 2) void pass2_kernel(
    const float* __restrict__ keys, const float* __restrict__ blob,
    const float* __restrict__ a0, const float* __restrict__ W1,
    const float* __restrict__ b1, float* __restrict__ ws) {
    const int batch = blockIdx.x >> 1, chunk = blockIdx.x & 1;
    const int slot = blockIdx.x & (NSLOT - 1);
    const int tid = threadIdx.x, wave = tid >> 6, lane = tid & 63;
    const float* bA = blob + (size_t)batch * BLOB_B;
    const float* kbase = keys + ((size_t)batch * TT + chunk * CHUNK) * DD;

    __shared__ __align__(16) float kbuf[2][TILE * DD];
    __shared__ float2 lss0[C0];

    finalize0(tid, ws, lss0);

    float s1[C1], q1[C1];
#pragma unroll
    for (int c = 0; c < C1; ++c) { s1[c] = 0.f; q1[c] = 0.f; }

    stage_tile(kbase, kbuf[0], wave, lane);
    __syncthreads();
#pragma unroll 1
    for (int st = 0; st < SPB; ++st) {
        const int buf = st & 1;
        if (st + 1 < SPB)
            stage_tile(kbase + (size_t)(st + 1) * TILE * DD, kbuf[buf ^ 1],
                       wave, lane);
        float kk[DD];
        load_row_lds(&kbuf[buf][tid * DD], kk);
#pragma unroll
        for (int d = 0; d < DD; ++d) PIN(kk[d]);
        float h1[C1];
#pragma unroll
        for (int c = 0; c < C1; ++c) h1[c] = 0.f;
#pragma unroll
        for (int j = 0; j < C0; ++j) {
            const float* wr = bA + j * BLOB_J;
            const float* ur = W1 + j * C1;
            const float2 ss = lss0[j];
            const float al = a0[j];
            float hh = wr[20];
#pragma unroll
            for (int d = 0; d < DD; ++d) hh = fmaf(kk[d], wr[d], hh);
            float pr = fast_sigmoid(fmaf(hh, ss.x, ss.y));
            float h0d = hh * fmaf(pr, 1.0f - al, al);
#pragma unroll
            for (int c = 0; c < C1; ++c) h1[c] = fmaf(h0d, ur[c], h1[c]);
        }
#pragma unroll
        for (int c = 0; c < C1; ++c) {
            float v = h1[c] + b1[c];
            s1[c] += v;
            q1[c] = fmaf(v, v, q1[c]);
        }
        __syncthreads();
    }
    float redv = 0.f;
#pragma unroll
    for (int v = 0; v < 2 * C1; ++v) {
        float val = (v < C1) ? s1[v] : q1[v - C1];
#pragma unroll
        for (int o = 32; o >= 1; o >>= 1) val += __shfl_xor(val, o);
        if (lane == v) redv = val;
    }
    if (lane < 2 * C1)
        atomicAdd(&ws[WS_P2 + slot * (2 * C1) + lane], redv);
}

// ---------------- pass 3: full tower + weighted key-sum ----------------
__global__ __launch_bounds__(NTH, 2) void pass3_kernel(
    const float* __restrict__ keys, const float* __restrict__ blob,
    const float* __restrict__ a0, const float* __restrict__ W1,
    const float* __restrict__ b1, const float* __restrict__ a1,
    const float* __restrict__ wk, const float* __restrict__ bk,
    float* __restrict__ ws, float* __restrict__ out) {
    const int batch = blockIdx.x >> 1, chunk = blockIdx.x & 1;
    const int tid = threadIdx.x, wave = tid >> 6, lane = tid & 63;
    const float* bA = blob + (size_t)batch * BLOB_B;
    const float* kbase = keys + ((size_t)batch * TT + chunk * CHUNK) * DD;

    __shared__ __align__(16) float kbuf[2][TILE * DD];
    __shared__ float2 lss0[C0];
    __shared__ float4 ld1v[C1];
    __shared__ float red[4][DD];

    finalize0(tid, ws, lss0);
    finalize1(tid, ws, a1, wk, ld1v);

    const float bkv = bk[0];
    float oacc[DD];
#pragma unroll
    for (int d = 0; d < DD; ++d) oacc[d] = 0.f;

    stage_tile(kbase, kbuf[0], wave, lane);
    __syncthreads();
#pragma unroll 1
    for (int st = 0; st < SPB; ++st) {
        const int buf = st & 1;
        if (st + 1 < SPB)
            stage_tile(kbase + (size_t)(st + 1) * TILE * DD, kbuf[buf ^ 1],
                       wave, lane);
        float kk[DD];
        load_row_lds(&kbuf[buf][tid * DD], kk);
#pragma unroll
        for (int d = 0; d < DD; ++d) PIN(kk[d]);
        float h1[C1];
#pragma unroll
        for (int c = 0; c < C1; ++c) h1[c] = 0.f;
#pragma unroll
        for (int j = 0; j < C0; ++j) {
            const float* wr = bA + j * BLOB_J;
            const float* ur = W1 + j * C1;
            const float2 ss = lss0[j];
            const float al = a0[j];
            float hh = wr[20];
#pragma unroll
            for (int d = 0; d < DD; ++d) hh = fmaf(kk[d], wr[d], hh);
            float pr = fast_sigmoid(fmaf(hh, ss.x, ss.y));
            float h0d = hh * fmaf(pr, 1.0f - al, al);
#pragma unroll
            for (int c = 0; c < C1; ++c) h1[c] = fmaf(h0d, ur[c], h1[c]);
        }
        float score = bkv;
#pragma unroll
        for (int c = 0; c < C1; ++c) {
            float v = h1[c] + b1[c];
            float4 dv = ld1v[c];
            float pr = fast_sigmoid(fmaf(v, dv.x, dv.y));
            float hd = v * fmaf(pr, 1.0f - dv.z, dv.z);
            score = fmaf(hd, dv.w, score);
        }
#pragma unroll
        for (int d = 0; d < DD; ++d) oacc[d] = fmaf(score, kk[d], oacc[d]);
        __syncthreads();
    }
    float redv = 0.f;
#pragma unroll
    for (int v = 0; v < DD; ++v) {
        float val = oacc[v];
#pragma unroll
        for (int o = 32; o >= 1; o >>= 1) val += __shfl_xor(val, o);
        if (lane == v) redv = val;
    }
    if (lane < DD) red[wave][lane] = redv;
    __syncthreads();
    if (tid < DD)
        atomicAdd(&out[batch * DD + tid],
                  red[0][tid] + red[1][tid] + red[2][tid] + red[3][tid]);
}

extern "C" void kernel_launch(void* const* d_in, const int* in_sizes, int n_in,
                              void* d_out, int out_size, void* d_ws,
                              size_t ws_size, hipStream_t stream) {
    const float* keys = (const float*)d_in[0];
    const float* query = (const float*)d_in[1];
    // d_in[2] = mask: intentionally unused
    const float* W0 = (const float*)d_in[3];
    const float* b0 = (const float*)d_in[4];
    const float* a0 = (const float*)d_in[5];
    const float* W1 = (const float*)d_in[6];
    const float* b1 = (const float*)d_in[7];
    const float* a1 = (const float*)d_in[8];
    const float* wk = (const float*)d_in[9];
    const float* bk = (const float*)d_in[10];
    float* out = (float*)d_out;
    float* ws = (float*)d_ws;
    float* blob = ws + WS_BLOB;  // 512*768 floats = 1.5 MB scratch

    prep_kernel<<<BB / 2, 64, 0, stream>>>(query, W0, b0, blob, ws, out);
    pass1_kernel<<<GRID, NTH, 0, stream>>>(keys, blob, ws);
    pass2_kernel<<<GRID, NTH, 0, stream>>>(keys, blob, a0, W1, b1, ws);
    pass3_kernel<<<GRID, NTH, 0, stream>>>(keys, blob, a0, W1, b1, a1, wk,
                                           bk, ws, out);
}